// Round 1
// baseline (544.111 us; speedup 1.0000x reference)
//
#include <hip/hip_runtime.h>
#include <math.h>

// Problem shapes (fixed by reference setup_inputs):
//   features  : [B=8, C=20, H=512, W=1024] fp32
//   prototypes: [M=20, C=20] fp32
//   distance_scale: [1] fp32
//   out       : [B=8, M=20, H=512, W=1024] fp32
// Memory-bound: 335.5 MB in + 335.5 MB out -> ~106 us floor @ 6.3 TB/s.

#define NC 20                       // channels == classes
#define HW_C (512 * 1024)           // H*W = 524288 = 2^19
#define HW_SHIFT 19
#define CHW_C (NC * HW_C)

__global__ __launch_bounds__(256) void isomax_dist_kernel(
    const float* __restrict__ feat,
    const float* __restrict__ protos,
    const float* __restrict__ dscale,
    float* __restrict__ out,
    int n_groups)
{
    __shared__ float s_pn[NC][NC];   // normalized prototypes, row-major [m][c]
    __shared__ float s_psq[NC];      // sum(pn^2) per prototype
    __shared__ float s_scale;

    const int tid = threadIdx.x;

    // Redundant per-block prototype normalization (400 floats, L2-cached).
    if (tid < NC) {
        float row[NC];
        float sq = 0.f;
#pragma unroll
        for (int c = 0; c < NC; ++c) {
            float v = protos[tid * NC + c];
            row[c] = v;
            sq += v * v;
        }
        float inv = 1.f / fmaxf(sqrtf(sq), 1e-12f);
        float psq = 0.f;
#pragma unroll
        for (int c = 0; c < NC; ++c) {
            float v = row[c] * inv;
            s_pn[tid][c] = v;
            psq += v * v;
        }
        s_psq[tid] = psq;
        if (tid == 0) s_scale = fabsf(dscale[0]);
    }
    __syncthreads();

    const int g = blockIdx.x * blockDim.x + tid;   // group of 4 pixels
    if (g >= n_groups) return;
    const int p0 = g << 2;                         // first pixel (linear over B*H*W)
    const int b  = p0 >> HW_SHIFT;
    const int hw = p0 & (HW_C - 1);

    const float* inbase = feat + (size_t)b * CHW_C + hw;

    // Load 20 channels x 4 pixels. Each float4 load is wave-coalesced (1 KiB).
    float4 x[NC];
#pragma unroll
    for (int c = 0; c < NC; ++c) {
        x[c] = *(const float4*)(inbase + (size_t)c * HW_C);
    }

    // ||x||^2 per pixel
    float4 xsq = make_float4(0.f, 0.f, 0.f, 0.f);
#pragma unroll
    for (int c = 0; c < NC; ++c) {
        xsq.x = fmaf(x[c].x, x[c].x, xsq.x);
        xsq.y = fmaf(x[c].y, x[c].y, xsq.y);
        xsq.z = fmaf(x[c].z, x[c].z, xsq.z);
        xsq.w = fmaf(x[c].w, x[c].w, xsq.w);
    }

    float4 inv;
    inv.x = 1.f / fmaxf(sqrtf(xsq.x), 1e-12f);
    inv.y = 1.f / fmaxf(sqrtf(xsq.y), 1e-12f);
    inv.z = 1.f / fmaxf(sqrtf(xsq.z), 1e-12f);
    inv.w = 1.f / fmaxf(sqrtf(xsq.w), 1e-12f);

    // ||xn||^2 = ||x||^2 * inv^2 (== 1 unless x ~ 0; matches ref numerics closely)
    float4 xnsq;
    xnsq.x = xsq.x * inv.x * inv.x;
    xnsq.y = xsq.y * inv.y * inv.y;
    xnsq.z = xsq.z * inv.z * inv.z;
    xnsq.w = xsq.w * inv.w * inv.w;

    const float scale = s_scale;
    float* obase = out + (size_t)b * CHW_C + hw;

#pragma unroll
    for (int m = 0; m < NC; ++m) {
        float4 dot = make_float4(0.f, 0.f, 0.f, 0.f);
#pragma unroll
        for (int c = 0; c < NC; ++c) {
            const float p = s_pn[m][c];   // broadcast across lanes: conflict-free
            dot.x = fmaf(x[c].x, p, dot.x);
            dot.y = fmaf(x[c].y, p, dot.y);
            dot.z = fmaf(x[c].z, p, dot.z);
            dot.w = fmaf(x[c].w, p, dot.w);
        }
        const float psq = s_psq[m];
        float4 o;
        // sq = max(xnsq + psq - 2*inv*dot, 0); out = -scale*sqrt(sq)
        o.x = -scale * sqrtf(fmaxf(fmaf(-2.f * inv.x, dot.x, xnsq.x + psq), 0.f));
        o.y = -scale * sqrtf(fmaxf(fmaf(-2.f * inv.y, dot.y, xnsq.y + psq), 0.f));
        o.z = -scale * sqrtf(fmaxf(fmaf(-2.f * inv.z, dot.z, xnsq.z + psq), 0.f));
        o.w = -scale * sqrtf(fmaxf(fmaf(-2.f * inv.w, dot.w, xnsq.w + psq), 0.f));
        *(float4*)(obase + (size_t)m * HW_C) = o;
    }
}

extern "C" void kernel_launch(void* const* d_in, const int* in_sizes, int n_in,
                              void* d_out, int out_size, void* d_ws, size_t ws_size,
                              hipStream_t stream) {
    (void)in_sizes; (void)n_in; (void)out_size; (void)d_ws; (void)ws_size;
    const float* feat   = (const float*)d_in[0];
    const float* protos = (const float*)d_in[1];
    const float* dscale = (const float*)d_in[2];
    float* out = (float*)d_out;

    const int B = 8;
    const int n_pixels = B * HW_C;          // 4,194,304
    const int n_groups = n_pixels / 4;      // 1,048,576 (exact)
    const int block = 256;
    const int grid  = n_groups / block;     // 4096 (exact)

    isomax_dist_kernel<<<grid, block, 0, stream>>>(feat, protos, dscale, out, n_groups);
}